// Round 1
// baseline (665.497 us; speedup 1.0000x reference)
//
#include <hip/hip_runtime.h>
#include <stdint.h>

#define NN 50000
#define NE 600000
#define CH 128

typedef __attribute__((ext_vector_type(8))) short short8;   // 8 bf16 (lax vector conversion to v8bf16 at the builtin)
typedef __attribute__((ext_vector_type(4))) float f32x4;

__device__ __forceinline__ ushort f2bf(float f) {
  union { float f; uint32_t u; } v; v.f = f;
  uint32_t u = v.u;
  return (ushort)((u + 0x7FFFu + ((u >> 16) & 1u)) >> 16);  // RNE, inputs finite
}

// ---- prep: transpose weights to [N][K] bf16 in ws ----
// layout in wt (ushort): ew1T[128][384] @0, ew2T[128][128] @49152, nw1T[128][256] @65536, nw2T[128][128] @98304
__global__ void prep_weights_k(const float* __restrict__ ew1, const float* __restrict__ ew2,
                               const float* __restrict__ nw1, const float* __restrict__ nw2,
                               ushort* __restrict__ wt) {
  int i = blockIdx.x * 256 + threadIdx.x;
  if (i < 49152) {
    int n = i / 384, k = i - n * 384;
    wt[i] = f2bf(ew1[k * 128 + n]);
  } else if (i < 65536) {
    int j = i - 49152; int n = j >> 7, k = j & 127;
    wt[i] = f2bf(ew2[k * 128 + n]);
  } else if (i < 98304) {
    int j = i - 65536; int n = j >> 8, k = j & 255;
    wt[i] = f2bf(nw1[k * 128 + n]);
  } else if (i < 114688) {
    int j = i - 98304; int n = j >> 7, k = j & 127;
    wt[i] = f2bf(nw2[k * 128 + n]);
  }
}

__global__ void convert_x_k(const float* __restrict__ x, ushort* __restrict__ xb) {
  int i = blockIdx.x * 256 + threadIdx.x;          // over NN*CH/4 float4s
  if (i >= NN * CH / 4) return;
  const float4 f = reinterpret_cast<const float4*>(x)[i];
  ushort4 r;
  r.x = f2bf(f.x); r.y = f2bf(f.y); r.z = f2bf(f.z); r.w = f2bf(f.w);
  reinterpret_cast<ushort4*>(xb)[i] = r;
}

__global__ void histogram_k(const int* __restrict__ ei, unsigned* __restrict__ cnt) {
  int e = blockIdx.x * 256 + threadIdx.x;
  if (e < NE) atomicAdd(&cnt[ei[e]], 1u);
}

__global__ void finalize_k(float* __restrict__ out_x, const unsigned* __restrict__ cnt) {
  int i = blockIdx.x * 256 + threadIdx.x;          // over NN*CH/4 float4s
  if (i >= NN * CH / 4) return;
  int n = i >> 5;                                   // 32 float4 per row
  float c = fmaxf((float)cnt[n], 1.0f);
  float4 v = reinterpret_cast<float4*>(out_x)[i];
  v.x /= c; v.y /= c; v.z /= c; v.w /= c;
  reinterpret_cast<float4*>(out_x)[i] = v;
}

// one MFMA k-step across 8 n-tiles x 4 row-tiles, B from transposed bf16 weights [N][K]
__device__ __forceinline__ void mm_step(const ushort* __restrict__ wT, int K, int ks, int l15, int kg,
                                        const short8 a[4], f32x4 acc[4][8]) {
#pragma unroll
  for (int nt = 0; nt < 8; ++nt) {
    short8 b = *reinterpret_cast<const short8*>(wT + (nt * 16 + l15) * K + ks * 32 + kg);
#pragma unroll
    for (int rt = 0; rt < 4; ++rt)
      acc[rt][nt] = __builtin_amdgcn_mfma_f32_16x16x32_bf16(a[rt], b, acc[rt][nt], 0, 0, 0);
  }
}

// Fused edge-MLP + node-MLP + scatter. Each WAVE independently owns 64 edges
// (4 row-tiles of 16). No barriers. h1/e_out/h2 round-trip through a per-wave
// LDS buffer, row stride 136 bf16 (272 B) for uniform bank distribution.
__global__ __launch_bounds__(256, 2) void fused_k(
    const int* __restrict__ ei, const float* __restrict__ edge_attr,
    const ushort* __restrict__ wt,
    const float* __restrict__ eb1, const float* __restrict__ eb2,
    const float* __restrict__ nb1, const float* __restrict__ nb2,
    const ushort* __restrict__ xb,
    float* __restrict__ out_x, float* __restrict__ out_e)
{
  __shared__ ushort hbuf[4][64][136];
  const int lane = threadIdx.x & 63;
  const int widx = threadIdx.x >> 6;
  const int wtile = blockIdx.x * 4 + widx;
  if (wtile * 64 >= NE) return;
  const int base = wtile * 64;
  const int l15 = lane & 15;
  const int g = lane >> 4;
  const int kg = g * 8;
  ushort (*h)[136] = hbuf[widx];

  const ushort* ew1T = wt;
  const ushort* ew2T = wt + 49152;
  const ushort* nw1T = wt + 65536;
  const ushort* nw2T = wt + 98304;

  int rowA[4], colA[4], eA[4];
#pragma unroll
  for (int rt = 0; rt < 4; ++rt) {
    eA[rt] = base + rt * 16 + l15;
    rowA[rt] = ei[eA[rt]];
    colA[rt] = ei[NE + eA[rt]];
  }

  const f32x4 zero4 = {0.f, 0.f, 0.f, 0.f};
  f32x4 acc[4][8];

  // ================= GEMM1: h1 = relu([x[row]|x[col]|edge_attr] @ ew1 + eb1) =================
#pragma unroll
  for (int rt = 0; rt < 4; ++rt)
#pragma unroll
    for (int nt = 0; nt < 8; ++nt) acc[rt][nt] = zero4;

#pragma unroll
  for (int ks = 0; ks < 4; ++ks) {               // k 0..127: x[row]
    short8 a[4];
#pragma unroll
    for (int rt = 0; rt < 4; ++rt)
      a[rt] = *reinterpret_cast<const short8*>(xb + rowA[rt] * CH + ks * 32 + kg);
    mm_step(ew1T, 384, ks, l15, kg, a, acc);
  }
#pragma unroll
  for (int ks = 4; ks < 8; ++ks) {               // k 128..255: x[col]
    short8 a[4];
#pragma unroll
    for (int rt = 0; rt < 4; ++rt)
      a[rt] = *reinterpret_cast<const short8*>(xb + colA[rt] * CH + (ks - 4) * 32 + kg);
    mm_step(ew1T, 384, ks, l15, kg, a, acc);
  }
#pragma unroll
  for (int ks = 8; ks < 12; ++ks) {              // k 256..383: edge_attr (fp32 -> bf16 on the fly)
    short8 a[4];
#pragma unroll
    for (int rt = 0; rt < 4; ++rt) {
      const float* p = edge_attr + (size_t)eA[rt] * CH + (ks - 8) * 32 + kg;
      float4 f0 = *reinterpret_cast<const float4*>(p);
      float4 f1 = *reinterpret_cast<const float4*>(p + 4);
      short8 t;
      t[0] = (short)f2bf(f0.x); t[1] = (short)f2bf(f0.y); t[2] = (short)f2bf(f0.z); t[3] = (short)f2bf(f0.w);
      t[4] = (short)f2bf(f1.x); t[5] = (short)f2bf(f1.y); t[6] = (short)f2bf(f1.z); t[7] = (short)f2bf(f1.w);
      a[rt] = t;
    }
    mm_step(ew1T, 384, ks, l15, kg, a, acc);
  }
  // epilogue 1 -> LDS (C/D layout: row=(l>>4)*4+reg, col=l&15)
#pragma unroll
  for (int nt = 0; nt < 8; ++nt) {
    float bb = eb1[nt * 16 + l15];
#pragma unroll
    for (int rt = 0; rt < 4; ++rt)
#pragma unroll
      for (int r = 0; r < 4; ++r) {
        float v = fmaxf(acc[rt][nt][r] + bb, 0.f);
        h[rt * 16 + g * 4 + r][nt * 16 + l15] = f2bf(v);
      }
  }

  // ================= GEMM2: e_out = h1 @ ew2 + eb2 =================
#pragma unroll
  for (int rt = 0; rt < 4; ++rt)
#pragma unroll
    for (int nt = 0; nt < 8; ++nt) acc[rt][nt] = zero4;
#pragma unroll
  for (int ks = 0; ks < 4; ++ks) {
    short8 a[4];
#pragma unroll
    for (int rt = 0; rt < 4; ++rt)
      a[rt] = *reinterpret_cast<const short8*>(&h[rt * 16 + l15][ks * 32 + kg]);
    mm_step(ew2T, 128, ks, l15, kg, a, acc);
  }
  // epilogue 2: store new_edge_attr (fp32) + bf16 copy back to LDS for GEMM3
#pragma unroll
  for (int nt = 0; nt < 8; ++nt) {
    float bb = eb2[nt * 16 + l15];
#pragma unroll
    for (int rt = 0; rt < 4; ++rt)
#pragma unroll
      for (int r = 0; r < 4; ++r) {
        float v = acc[rt][nt][r] + bb;
        int erow = base + rt * 16 + g * 4 + r;
        out_e[(size_t)erow * CH + nt * 16 + l15] = v;
        h[rt * 16 + g * 4 + r][nt * 16 + l15] = f2bf(v);
      }
  }

  // ================= GEMM3: h2 = relu([x[col]|e_out] @ nw1 + nb1) =================
#pragma unroll
  for (int rt = 0; rt < 4; ++rt)
#pragma unroll
    for (int nt = 0; nt < 8; ++nt) acc[rt][nt] = zero4;
#pragma unroll
  for (int ks = 0; ks < 4; ++ks) {               // k 0..127: x[col]
    short8 a[4];
#pragma unroll
    for (int rt = 0; rt < 4; ++rt)
      a[rt] = *reinterpret_cast<const short8*>(xb + colA[rt] * CH + ks * 32 + kg);
    mm_step(nw1T, 256, ks, l15, kg, a, acc);
  }
#pragma unroll
  for (int ks = 4; ks < 8; ++ks) {               // k 128..255: e_out from LDS
    short8 a[4];
#pragma unroll
    for (int rt = 0; rt < 4; ++rt)
      a[rt] = *reinterpret_cast<const short8*>(&h[rt * 16 + l15][(ks - 4) * 32 + kg]);
    mm_step(nw1T, 256, ks, l15, kg, a, acc);
  }
  // epilogue 3 -> LDS
#pragma unroll
  for (int nt = 0; nt < 8; ++nt) {
    float bb = nb1[nt * 16 + l15];
#pragma unroll
    for (int rt = 0; rt < 4; ++rt)
#pragma unroll
      for (int r = 0; r < 4; ++r) {
        float v = fmaxf(acc[rt][nt][r] + bb, 0.f);
        h[rt * 16 + g * 4 + r][nt * 16 + l15] = f2bf(v);
      }
  }

  // ================= GEMM4: msg = h2 @ nw2 + nb2; scatter-add over row =================
#pragma unroll
  for (int rt = 0; rt < 4; ++rt)
#pragma unroll
    for (int nt = 0; nt < 8; ++nt) acc[rt][nt] = zero4;
#pragma unroll
  for (int ks = 0; ks < 4; ++ks) {
    short8 a[4];
#pragma unroll
    for (int rt = 0; rt < 4; ++rt)
      a[rt] = *reinterpret_cast<const short8*>(&h[rt * 16 + l15][ks * 32 + kg]);
    mm_step(nw2T, 128, ks, l15, kg, a, acc);
  }
  float bnb2[8];
#pragma unroll
  for (int nt = 0; nt < 8; ++nt) bnb2[nt] = nb2[nt * 16 + l15];
#pragma unroll
  for (int rt = 0; rt < 4; ++rt) {
#pragma unroll
    for (int r = 0; r < 4; ++r) {
      int rowc = ei[base + rt * 16 + g * 4 + r];
#pragma unroll
      for (int nt = 0; nt < 8; ++nt)
        atomicAdd(&out_x[rowc * CH + nt * 16 + l15], acc[rt][nt][r] + bnb2[nt]);
    }
  }
}

extern "C" void kernel_launch(void* const* d_in, const int* in_sizes, int n_in,
                              void* d_out, int out_size, void* d_ws, size_t ws_size,
                              hipStream_t stream) {
  const float* x   = (const float*)d_in[0];
  const int*   ei  = (const int*)d_in[1];
  const float* ea  = (const float*)d_in[2];
  const float* ew1 = (const float*)d_in[3];
  const float* eb1 = (const float*)d_in[4];
  const float* ew2 = (const float*)d_in[5];
  const float* eb2 = (const float*)d_in[6];
  const float* nw1 = (const float*)d_in[7];
  const float* nb1 = (const float*)d_in[8];
  const float* nw2 = (const float*)d_in[9];
  const float* nb2 = (const float*)d_in[10];

  float* out_x = (float*)d_out;                          // [NN][CH] (accumulated then divided)
  float* out_e = (float*)d_out + (size_t)NN * CH;        // [NE][CH]

  // ws layout: wt bf16 (229376 B) | xb bf16 (12.8 MB) | cnt u32 (200 KB)  => ~13.3 MB
  ushort*   wt  = (ushort*)d_ws;
  ushort*   xb  = (ushort*)((char*)d_ws + 229376);
  unsigned* cnt = (unsigned*)((char*)d_ws + 229376 + (size_t)NN * CH * 2);

  hipMemsetAsync(out_x, 0, (size_t)NN * CH * sizeof(float), stream);
  hipMemsetAsync(cnt, 0, (size_t)NN * sizeof(unsigned), stream);

  prep_weights_k<<<448, 256, 0, stream>>>(ew1, ew2, nw1, nw2, wt);
  convert_x_k<<<(NN * CH / 4 + 255) / 256, 256, 0, stream>>>(x, xb);
  histogram_k<<<(NE + 255) / 256, 256, 0, stream>>>(ei, cnt);

  int wave_tiles = NE / 64;                              // 9375
  fused_k<<<(wave_tiles + 3) / 4, 256, 0, stream>>>(ei, ea, wt, eb1, eb2, nb1, nb2, xb, out_x, out_e);

  finalize_k<<<(NN * CH / 4 + 255) / 256, 256, 0, stream>>>(out_x, cnt);
}